// Round 6
// baseline (209.299 us; speedup 1.0000x reference)
//
#include <hip/hip_runtime.h>
#include <math.h>

#define DM   1024
#define TTOK 2048
#define NTOK 4096   // B*T

typedef __bf16 bf16x8 __attribute__((ext_vector_type(8)));
typedef __bf16 bf16x4 __attribute__((ext_vector_type(4)));
typedef float  f32x4  __attribute__((ext_vector_type(4)));
typedef float  f32x16 __attribute__((ext_vector_type(16)));

// Q pre-scale: sm_scale (1/8) * log2(e)  -> allows p = exp2(s)
#define QSCALE 0.18033688011112042f

#if defined(__has_builtin)
#if __has_builtin(__builtin_amdgcn_exp2f)
#define EXP2F(x) __builtin_amdgcn_exp2f(x)
#endif
#endif
#ifndef EXP2F
#define EXP2F(x) exp2f(x)
#endif

#define GLDS16(g, l) __builtin_amdgcn_global_load_lds( \
    (__attribute__((address_space(1))) void*)(g),      \
    (__attribute__((address_space(3))) void*)(l), 16, 0, 0)

// ---------------- fp32 -> bf16 convert: x + 4 weights in ONE launch ----------------
__global__ __launch_bounds__(256)
void cvt_all(const float* __restrict__ x,  const float* __restrict__ Wq,
             const float* __restrict__ Wk, const float* __restrict__ Wv,
             const float* __restrict__ Wo, __bf16* __restrict__ dst) {
    size_t g = ((size_t)blockIdx.x * 256 + threadIdx.x) * 8;
    const float* s;
    size_t off;
    const size_t NX = (size_t)NTOK * DM;   // 4M
    if (g < NX) { s = x; off = g; }
    else {
        size_t gg = g - NX;
        int w = (int)(gg >> 20);           // 1M-element segments
        off = gg & ((1u << 20) - 1);
        s = (w == 0) ? Wq : (w == 1) ? Wk : (w == 2) ? Wv : Wo;
    }
    float4 a = *(const float4*)(s + off);
    float4 b = *(const float4*)(s + off + 4);
    bf16x8 v;
    v[0] = (__bf16)a.x; v[1] = (__bf16)a.y; v[2] = (__bf16)a.z; v[3] = (__bf16)a.w;
    v[4] = (__bf16)b.x; v[5] = (__bf16)b.y; v[6] = (__bf16)b.z; v[7] = (__bf16)b.w;
    *(bf16x8*)(dst + g) = v;
}

// =====================================================================
// bf16 MFMA GEMM, orientation chosen per output so C-layout's 4
// consecutive m-rows land on the FASTEST output axis (packed stores).
// MODE 0 (QKV, grid z):
//   z=0: C = Wq·x^T  (m=wdim, n=token) -> Q[b,h,t,d] *QSCALE, bf16x4 along d
//   z=1: C = Wk·x^T  -> K[b,h,t,d], bf16x4 along d
//   z=2: C = x·Wv^T  (m=token, n=wdim) -> Vt[b,h,d,t], bf16x4 along t
// MODE 1 (out-proj): C = Wo·Zm^T (m=Dout, n=token) -> out[token][D], float4
// =====================================================================
template<int MODE>
__global__ __launch_bounds__(256)
void gemm_bf16(const __bf16* __restrict__ X,
               const __bf16* __restrict__ W0, const __bf16* __restrict__ W1,
               const __bf16* __restrict__ W2,
               __bf16* __restrict__ Oq, __bf16* __restrict__ Ok,
               __bf16* __restrict__ Ovt, float* __restrict__ Of)
{
    const int z = (MODE == 0) ? blockIdx.z : 3;
    const __bf16 *A, *B;
    int m0, n0;
    if (MODE == 0 && z < 2) {        // W·x^T
        A = z ? W1 : W0; B = X;
        m0 = blockIdx.y * 128; n0 = blockIdx.x * 128;
    } else if (MODE == 0) {          // x·Wv^T
        A = X; B = W2;
        m0 = blockIdx.x * 128; n0 = blockIdx.y * 128;
    } else {                         // Wo·Zm^T
        A = W0; B = X;
        m0 = blockIdx.y * 128; n0 = blockIdx.x * 128;
    }

    __shared__ __attribute__((aligned(16))) __bf16 As[128 * 32];
    __shared__ __attribute__((aligned(16))) __bf16 Bs[128 * 32];

    const int tid  = threadIdx.x;
    const int lane = tid & 63;
    const int wave = tid >> 6;
    const int wm = wave & 1, wn = wave >> 1;
    const int col = lane & 15, quad = lane >> 4;

    const __bf16* Ag = A + (size_t)(m0 + (tid >> 2)) * DM + (tid & 3) * 8;
    const __bf16* Bg = B + (size_t)(n0 + (tid >> 2)) * DM + (tid & 3) * 8;
    __bf16* lA = As + tid * 8;
    __bf16* lB = Bs + tid * 8;

    f32x4 acc[4][4];
#pragma unroll
    for (int i = 0; i < 4; ++i)
#pragma unroll
        for (int j = 0; j < 4; ++j)
#pragma unroll
            for (int r = 0; r < 4; ++r) acc[i][j][r] = 0.0f;

    for (int k0 = 0; k0 < DM; k0 += 32) {
        __syncthreads();
        GLDS16(Ag + k0,                   lA);
        GLDS16(Ag + (size_t)64 * DM + k0, lA + 2048);
        GLDS16(Bg + k0,                   lB);
        GLDS16(Bg + (size_t)64 * DM + k0, lB + 2048);
        __syncthreads();
        bf16x8 af[4], bfr[4];
#pragma unroll
        for (int i = 0; i < 4; ++i)
            af[i] = *(const bf16x8*)&As[(wm * 64 + i * 16 + col) * 32 + quad * 8];
#pragma unroll
        for (int j = 0; j < 4; ++j)
            bfr[j] = *(const bf16x8*)&Bs[(wn * 64 + j * 16 + col) * 32 + quad * 8];
#pragma unroll
        for (int i = 0; i < 4; ++i)
#pragma unroll
            for (int j = 0; j < 4; ++j)
                acc[i][j] = __builtin_amdgcn_mfma_f32_16x16x32_bf16(af[i], bfr[j], acc[i][j], 0, 0, 0);
    }

#pragma unroll
    for (int i = 0; i < 4; ++i) {
#pragma unroll
        for (int j = 0; j < 4; ++j) {
            const int mb = m0 + wm * 64 + i * 16 + quad * 4;   // 4 consecutive m
            const int n  = n0 + wn * 64 + j * 16 + col;
            if (MODE == 1) {
                // m = Dout (fastest), n = token
                float4 st = make_float4(acc[i][j][0], acc[i][j][1],
                                        acc[i][j][2], acc[i][j][3]);
                *(float4*)&Of[(size_t)n * DM + mb] = st;
            } else if (z < 2) {
                // m = wdim -> (h,d), n = token -> (b,t); d fastest
                const int h = mb >> 6, d = mb & 63;
                const int b = n >> 11, t = n & 2047;
                const float sc = z ? 1.0f : QSCALE;
                bf16x4 pk;
#pragma unroll
                for (int r = 0; r < 4; ++r) pk[r] = (__bf16)(acc[i][j][r] * sc);
                *(bf16x4*)&((z ? Ok : Oq)[(((size_t)(b * 16 + h)) * TTOK + t) * 64 + d]) = pk;
            } else {
                // m = token -> (b,t), n = wdim -> (h,d); t fastest
                const int b = mb >> 11, t = mb & 2047;
                const int h = n >> 6,  d = n & 63;
                bf16x4 pk;
#pragma unroll
                for (int r = 0; r < 4; ++r) pk[r] = (__bf16)acc[i][j][r];
                *(bf16x4*)&Ovt[(((size_t)(b * 16 + h)) * 64 + d) * TTOK + t] = pk;
            }
        }
    }
}

// =====================================================================
// MFMA flash attention v5: 32x32x16 frags (2x FLOP per LDS byte).
// 256 threads (4 waves), 128 q/block, 32 q/wave.
// S^T = K·Q^T (M=keys, N=q); p = exp2 (log2e folded into Q);
// l = mfma(ones, P, l); O^T = V^T·P; exclusive-mod epilogue.
// LDS 36 KB: Ks/Vs 9K ([key][d] / [d][key], stride 72) + QPs 18K
// (Q stage [q][d] -> per-wave P region [q][key]).
// =====================================================================
__global__ __launch_bounds__(256)
void attn_mfma(const __bf16* __restrict__ Qg, const __bf16* __restrict__ Kg,
               const __bf16* __restrict__ Vtg, __bf16* __restrict__ Zm)
{
    const int bh = blockIdx.y;
    const int q0 = blockIdx.x * 128;
    const size_t base = (size_t)bh * TTOK * 64;

    __shared__ __attribute__((aligned(16))) __bf16 Ks[64 * 72];
    __shared__ __attribute__((aligned(16))) __bf16 Vs[64 * 72];
    __shared__ __attribute__((aligned(16))) __bf16 QPs[128 * 72];

    const int tid  = threadIdx.x;
    const int lane = tid & 63, wave = tid >> 6;   // wave 0..3
    const int c32  = lane & 31, h32 = lane >> 5;

    // ---- stage Q (pre-scaled by QSCALE in GEMM): 128 rows x 64 ----
#pragma unroll
    for (int it = 0; it < 2; ++it) {
        int idx = tid + 256 * it;              // 0..511
        int r = idx >> 2, off = (idx & 3) * 16;
        const __bf16* src = Qg + base + (size_t)(q0 + r) * 64 + off;
        *(bf16x8*)&QPs[r * 72 + off]     = *(const bf16x8*)(src);
        *(bf16x8*)&QPs[r * 72 + off + 8] = *(const bf16x8*)(src + 8);
    }
    __syncthreads();
    // hoist Q B-frags: B[k=d][n=q], lane: q = c32, k = h32*8 + j + st*16
    bf16x8 qf[4];
#pragma unroll
    for (int st = 0; st < 4; ++st)
        qf[st] = *(const bf16x8*)&QPs[(wave * 32 + c32) * 72 + h32 * 8 + st * 16];
    // wave w reuses rows [32w,32w+32) as its P region (only rows it read)

    bf16x8 ones;
#pragma unroll
    for (int i = 0; i < 8; ++i) ones[i] = (__bf16)1.0f;

    f32x16 O[2], lacc;
#pragma unroll
    for (int r = 0; r < 16; ++r) { O[0][r] = 0.0f; O[1][r] = 0.0f; lacc[r] = 0.0f; }

    const int rs = tid >> 2, soff = (tid & 3) * 16;   // 64 rows x 64, 2 b128/thread

    // prefetch tile 0
    bf16x8 kr0 = *(const bf16x8*)(Kg  + base + (size_t)rs * 64 + soff);
    bf16x8 kr1 = *(const bf16x8*)(Kg  + base + (size_t)rs * 64 + soff + 8);
    bf16x8 vr0 = *(const bf16x8*)(Vtg + base + (size_t)rs * TTOK + soff);
    bf16x8 vr1 = *(const bf16x8*)(Vtg + base + (size_t)rs * TTOK + soff + 8);

    // epilogue V snapshot coords: wave's q-rows live in key-tile kb_tgt
    const int kb_tgt = (q0 >> 6) + (wave >> 1);
    const int qo     = (wave & 1) * 32 + c32;
    float vq[2][16];

    for (int kb = 0; kb < TTOK / 64; ++kb) {
        __syncthreads();   // prior tile's Ks/Vs frag reads complete
        *(bf16x8*)&Ks[rs * 72 + soff]     = kr0;
        *(bf16x8*)&Ks[rs * 72 + soff + 8] = kr1;
        *(bf16x8*)&Vs[rs * 72 + soff]     = vr0;
        *(bf16x8*)&Vs[rs * 72 + soff + 8] = vr1;
        __syncthreads();

        // prefetch next tile — latency spans the compute below
        {
            int kbn = (kb + 1) & (TTOK / 64 - 1);
            const __bf16* kp = Kg  + base + (size_t)(kbn * 64 + rs) * 64 + soff;
            const __bf16* vp = Vtg + base + (size_t)rs * TTOK + kbn * 64 + soff;
            kr0 = *(const bf16x8*)(kp); kr1 = *(const bf16x8*)(kp + 8);
            vr0 = *(const bf16x8*)(vp); vr1 = *(const bf16x8*)(vp + 8);
        }

        // ---- S^T = K·Q^T : A[m=key][k=d] from Ks, 2 key-blocks ----
        f32x16 s0, s1;
#pragma unroll
        for (int r = 0; r < 16; ++r) { s0[r] = 0.0f; s1[r] = 0.0f; }
#pragma unroll
        for (int st = 0; st < 4; ++st) {
            bf16x8 a0 = *(const bf16x8*)&Ks[(c32)      * 72 + h32 * 8 + st * 16];
            bf16x8 a1 = *(const bf16x8*)&Ks[(32 + c32) * 72 + h32 * 8 + st * 16];
            s0 = __builtin_amdgcn_mfma_f32_32x32x16_bf16(a0, qf[st], s0, 0, 0, 0);
            s1 = __builtin_amdgcn_mfma_f32_32x32x16_bf16(a1, qf[st], s1, 0, 0, 0);
        }

        // ---- p = exp2(s); write P[q][key] (b64 packs of 4 consecutive keys) ----
#pragma unroll
        for (int kb2 = 0; kb2 < 2; ++kb2) {
#pragma unroll
            for (int g = 0; g < 4; ++g) {
                float p0 = EXP2F(kb2 ? s1[4 * g + 0] : s0[4 * g + 0]);
                float p1 = EXP2F(kb2 ? s1[4 * g + 1] : s0[4 * g + 1]);
                float p2 = EXP2F(kb2 ? s1[4 * g + 2] : s0[4 * g + 2]);
                float p3 = EXP2F(kb2 ? s1[4 * g + 3] : s0[4 * g + 3]);
                bf16x4 pk;
                pk[0] = (__bf16)p0; pk[1] = (__bf16)p1;
                pk[2] = (__bf16)p2; pk[3] = (__bf16)p3;
                *(bf16x4*)&QPs[(wave * 32 + c32) * 72 + kb2 * 32 + g * 8 + h32 * 4] = pk;
            }
        }

        // ---- O^T += V^T·P ; l += 1·P  (all intra-wave) ----
#pragma unroll
        for (int ks = 0; ks < 4; ++ks) {
            bf16x8 pf = *(const bf16x8*)&QPs[(wave * 32 + c32) * 72 + h32 * 8 + ks * 16];
            lacc = __builtin_amdgcn_mfma_f32_32x32x16_bf16(ones, pf, lacc, 0, 0, 0);
            bf16x8 v0 = *(const bf16x8*)&Vs[(c32)      * 72 + h32 * 8 + ks * 16];
            bf16x8 v1 = *(const bf16x8*)&Vs[(32 + c32) * 72 + h32 * 8 + ks * 16];
            O[0] = __builtin_amdgcn_mfma_f32_32x32x16_bf16(v0, pf, O[0], 0, 0, 0);
            O[1] = __builtin_amdgcn_mfma_f32_32x32x16_bf16(v1, pf, O[1], 0, 0, 0);
        }

        // ---- snapshot own-q V column from LDS (wave-uniform branch) ----
        if (kb == kb_tgt) {
#pragma unroll
            for (int db = 0; db < 2; ++db)
#pragma unroll
                for (int rg = 0; rg < 16; ++rg) {
                    int d = db * 32 + (rg & 3) + 8 * (rg >> 2) + 4 * h32;
                    vq[db][rg] = (float)Vs[d * 72 + qo];
                }
        }
    }

    // every lane holds l[q = c32] in each lacc component
    const float inv = 1.0f / lacc[0];

    // ---- epilogue: Y = O/l ; exclusive output mod ; packed bf16 store ----
    const int b = bh >> 4, h = bh & 15;
    const int q = q0 + wave * 32 + c32;
    float y[2][16];
    float yv = 0.f, v2 = 0.f, yy = 0.f;
#pragma unroll
    for (int db = 0; db < 2; ++db)
#pragma unroll
        for (int rg = 0; rg < 16; ++rg) {
            float yval = O[db][rg] * inv;
            float vval = vq[db][rg];
            y[db][rg] = yval;
            yv += yval * vval; v2 += vval * vval; yy += yval * yval;
        }
    yv += __shfl_xor(yv, 32, 64);
    v2 += __shfl_xor(v2, 32, 64);
    yy += __shfl_xor(yy, 32, 64);
    float scl = (v2 > 0.0f) ? yv / fmaxf(v2, 1.1754943508222875e-38f) : 0.0f;
    float zz = 0.f;
    float zvv[2][16];
#pragma unroll
    for (int db = 0; db < 2; ++db)
#pragma unroll
        for (int rg = 0; rg < 16; ++rg) {
            zvv[db][rg] = y[db][rg] - scl * vq[db][rg];
            zz += zvv[db][rg] * zvv[db][rg];
        }
    zz += __shfl_xor(zz, 32, 64);
    float znorm = sqrtf(zz);
    float refn  = fmaxf(sqrtf(yy), sqrtf(v2));
    bool  wipe  = (v2 > 0.0f) && (znorm <= 1.1920928955078125e-07f * 64.0f * refn);
#pragma unroll
    for (int db = 0; db < 2; ++db)
#pragma unroll
        for (int g = 0; g < 4; ++g) {
            bf16x4 pk;
#pragma unroll
            for (int r = 0; r < 4; ++r)
                pk[r] = (__bf16)(wipe ? 0.0f : zvv[db][4 * g + r]);
            int d = db * 32 + 8 * g + 4 * h32;
            *(bf16x4*)&Zm[((size_t)(b * TTOK + q)) * DM + h * 64 + d] = pk;
        }
}

// =====================================================================
extern "C" void kernel_launch(void* const* d_in, const int* in_sizes, int n_in,
                              void* d_out, int out_size, void* d_ws, size_t ws_size,
                              hipStream_t stream) {
    const float* x  = (const float*)d_in[0];
    const float* Wq = (const float*)d_in[1];
    const float* Wk = (const float*)d_in[2];
    const float* Wv = (const float*)d_in[3];
    const float* Wo = (const float*)d_in[4];

    const size_t NX = (size_t)NTOK * DM;   // 4M
    const size_t NW = (size_t)DM * DM;     // 1M
    __bf16* xb  = (__bf16*)d_ws;
    __bf16* wqb = xb  + NX;
    __bf16* wkb = wqb + NW;
    __bf16* wvb = wkb + NW;
    __bf16* wob = wvb + NW;
    __bf16* Qb  = wob + NW;
    __bf16* Kb  = Qb  + NX;
    __bf16* Vtb = Kb  + NX;
    __bf16* Zmb = Vtb + NX;   // total 24M bf16 = 48 MB

    cvt_all<<<(NX + 4 * NW) / 2048, 256, 0, stream>>>(x, Wq, Wk, Wv, Wo, xb);

    // QKV: z0/z1 = Wq,Wk · x^T ; z2 = x · Wv^T
    gemm_bf16<0><<<dim3(32, 8, 3), 256, 0, stream>>>(
        xb, wqb, wkb, wvb, Qb, Kb, Vtb, nullptr);

    attn_mfma<<<dim3(TTOK / 128, 32), 256, 0, stream>>>(Qb, Kb, Vtb, Zmb);

    // out = (Wo · Zm^T)^T
    gemm_bf16<1><<<dim3(32, 8, 1), 256, 0, stream>>>(
        Zmb, wob, nullptr, nullptr, nullptr, nullptr, nullptr, (float*)d_out);
}

// Round 7
// 190.242 us; speedup vs baseline: 1.1002x; 1.1002x over previous
//
#include <hip/hip_runtime.h>
#include <math.h>

#define DM   1024
#define TTOK 2048
#define NTOK 4096   // B*T

typedef __bf16 bf16x8 __attribute__((ext_vector_type(8)));
typedef __bf16 bf16x4 __attribute__((ext_vector_type(4)));
typedef float  f32x4  __attribute__((ext_vector_type(4)));
typedef float  f32x16 __attribute__((ext_vector_type(16)));

// Q pre-scale: sm_scale (1/8) * log2(e)  -> allows p = exp2(s)
#define QSCALE 0.18033688011112042f

#if defined(__has_builtin)
#if __has_builtin(__builtin_amdgcn_exp2f)
#define EXP2F(x) __builtin_amdgcn_exp2f(x)
#endif
#endif
#ifndef EXP2F
#define EXP2F(x) exp2f(x)
#endif

#define GLDS16(g, l) __builtin_amdgcn_global_load_lds( \
    (__attribute__((address_space(1))) void*)(g),      \
    (__attribute__((address_space(3))) void*)(l), 16, 0, 0)

// ---------------- fp32 -> bf16 convert: x + 4 weights in ONE launch ----------------
__global__ __launch_bounds__(256)
void cvt_all(const float* __restrict__ x,  const float* __restrict__ Wq,
             const float* __restrict__ Wk, const float* __restrict__ Wv,
             const float* __restrict__ Wo, __bf16* __restrict__ dst) {
    size_t g = ((size_t)blockIdx.x * 256 + threadIdx.x) * 8;
    const float* s;
    size_t off;
    const size_t NX = (size_t)NTOK * DM;   // 4M
    if (g < NX) { s = x; off = g; }
    else {
        size_t gg = g - NX;
        int w = (int)(gg >> 20);           // 1M-element segments
        off = gg & ((1u << 20) - 1);
        s = (w == 0) ? Wq : (w == 1) ? Wk : (w == 2) ? Wv : Wo;
    }
    float4 a = *(const float4*)(s + off);
    float4 b = *(const float4*)(s + off + 4);
    bf16x8 v;
    v[0] = (__bf16)a.x; v[1] = (__bf16)a.y; v[2] = (__bf16)a.z; v[3] = (__bf16)a.w;
    v[4] = (__bf16)b.x; v[5] = (__bf16)b.y; v[6] = (__bf16)b.z; v[7] = (__bf16)b.w;
    *(bf16x8*)(dst + g) = v;
}

// =====================================================================
// bf16 MFMA GEMM: C[m,n] = sum_k A[m,k] * B[n,k], 128x128 tile, BK=32.
// MODE 0 (QKV, grid z) with LDS-transpose epilogue (packed 16B stores):
//   z=0: A=Wq, B=x (m=hd, n=token) -> Q[b,h,t,d] * QSCALE
//   z=1: A=Wk, B=x                  -> K[b,h,t,d]
//   z=2: A=x,  B=Wv (m=token, n=hd) -> Vt[b,h,d,t]
// MODE 1 (out-proj): A=Zm (m=token), B=Wo (n=Dout) -> out[t][D] fp32,
//   scalar n-fastest stores (64B-contiguous per 16 lanes).
// =====================================================================
#define LSTR 136   // LDS transpose stride (16B-aligned rows, conflict-free)

template<int MODE>
__global__ __launch_bounds__(256)
void gemm_bf16(const __bf16* __restrict__ X,
               const __bf16* __restrict__ W0, const __bf16* __restrict__ W1,
               const __bf16* __restrict__ W2,
               __bf16* __restrict__ Oq, __bf16* __restrict__ Ok,
               __bf16* __restrict__ Ovt, float* __restrict__ Of)
{
    const int z = (MODE == 0) ? blockIdx.z : 3;
    const __bf16 *A, *B;
    int m0, n0;
    if (MODE == 0 && z < 2) {        // W·x^T : m=hd(1024), n=token(4096)
        A = z ? W1 : W0; B = X;
        m0 = blockIdx.y * 128; n0 = blockIdx.x * 128;
    } else if (MODE == 0) {          // x·Wv^T : m=token, n=hd
        A = X; B = W2;
        m0 = blockIdx.x * 128; n0 = blockIdx.y * 128;
    } else {                         // Zm·Wo^T : m=token(4096), n=Dout(1024)
        A = X; B = W0;
        m0 = blockIdx.y * 128; n0 = blockIdx.x * 128;
    }

    // union: staging (As 4K + Bs 4K elems) / 128x136 transpose buffer
    __shared__ __attribute__((aligned(16))) __bf16 smem[128 * LSTR];
    __bf16* As = smem;
    __bf16* Bs = smem + 128 * 32;

    const int tid  = threadIdx.x;
    const int lane = tid & 63;
    const int wave = tid >> 6;
    const int wm = wave & 1, wn = wave >> 1;
    const int col = lane & 15, quad = lane >> 4;

    const __bf16* Ag = A + (size_t)(m0 + (tid >> 2)) * DM + (tid & 3) * 8;
    const __bf16* Bg = B + (size_t)(n0 + (tid >> 2)) * DM + (tid & 3) * 8;
    __bf16* lA = As + tid * 8;
    __bf16* lB = Bs + tid * 8;

    f32x4 acc[4][4];
#pragma unroll
    for (int i = 0; i < 4; ++i)
#pragma unroll
        for (int j = 0; j < 4; ++j)
#pragma unroll
            for (int r = 0; r < 4; ++r) acc[i][j][r] = 0.0f;

    for (int k0 = 0; k0 < DM; k0 += 32) {
        __syncthreads();
        GLDS16(Ag + k0,                   lA);
        GLDS16(Ag + (size_t)64 * DM + k0, lA + 2048);
        GLDS16(Bg + k0,                   lB);
        GLDS16(Bg + (size_t)64 * DM + k0, lB + 2048);
        __syncthreads();
        bf16x8 af[4], bfr[4];
#pragma unroll
        for (int i = 0; i < 4; ++i)
            af[i] = *(const bf16x8*)&As[(wm * 64 + i * 16 + col) * 32 + quad * 8];
#pragma unroll
        for (int j = 0; j < 4; ++j)
            bfr[j] = *(const bf16x8*)&Bs[(wn * 64 + j * 16 + col) * 32 + quad * 8];
#pragma unroll
        for (int i = 0; i < 4; ++i)
#pragma unroll
            for (int j = 0; j < 4; ++j)
                acc[i][j] = __builtin_amdgcn_mfma_f32_16x16x32_bf16(af[i], bfr[j], acc[i][j], 0, 0, 0);
    }

    if (MODE == 1) {
        // scalar n-fastest fp32 stores: 16 lanes = 64B contiguous
#pragma unroll
        for (int i = 0; i < 4; ++i)
#pragma unroll
            for (int j = 0; j < 4; ++j) {
                const int mb = m0 + wm * 64 + i * 16 + quad * 4;
                const int n  = n0 + wn * 64 + j * 16 + col;
#pragma unroll
                for (int r = 0; r < 4; ++r)
                    Of[(size_t)(mb + r) * DM + n] = acc[i][j][r];
            }
        return;
    }

    // ---- MODE 0: LDS transpose -> packed global stores ----
    const float sc = (z == 0) ? QSCALE : 1.0f;
    __syncthreads();   // staging reads done; smem reusable
#pragma unroll
    for (int i = 0; i < 4; ++i)
#pragma unroll
        for (int j = 0; j < 4; ++j) {
            const int ml = wm * 64 + i * 16 + quad * 4;
            const int nl = wn * 64 + j * 16 + col;
            bf16x4 pk;
#pragma unroll
            for (int r = 0; r < 4; ++r) pk[r] = (__bf16)(acc[i][j][r] * sc);
            *(bf16x4*)&smem[nl * LSTR + ml] = pk;   // Ls[n][m]
        }
    __syncthreads();

    // 128 rows x 16 chunks of 8 elems = 2048 chunks; 8 iterations x 256 thr
#pragma unroll
    for (int it = 0; it < 8; ++it) {
        int c   = tid + 256 * it;
        int row = c >> 4;          // n_local
        int ch  = (c & 15) * 8;    // m_local base
        bf16x8 v = *(const bf16x8*)&smem[row * LSTR + ch];
        if (z < 2) {
            // row = token, ch = hd: d-contiguous segments of Q/K[b,h,t,d]
            int t  = n0 + row;
            int b  = t >> 11; t &= 2047;
            int hd = m0 + ch;
            int h  = hd >> 6, d = hd & 63;
            *(bf16x8*)&((z ? Ok : Oq)[(((size_t)(b * 16 + h)) * TTOK + t) * 64 + d]) = v;
        } else {
            // row = hd, ch = token: t-contiguous segments of Vt[b,h,d,t]
            int hd = n0 + row;
            int h  = hd >> 6, d = hd & 63;
            int t  = m0 + ch;
            int b  = t >> 11; t &= 2047;
            *(bf16x8*)&Ovt[(((size_t)(b * 16 + h)) * 64 + d) * TTOK + t] = v;
        }
    }
}

// =====================================================================
// MFMA flash attention v5: 32x32x16 frags (2x FLOP per LDS byte).
// 256 threads (4 waves), 128 q/block, 32 q/wave.
// S^T = K·Q^T (M=keys, N=q); p = exp2 (log2e folded into Q);
// l = mfma(ones, P, l); O^T = V^T·P; exclusive-mod epilogue.
// LDS 36 KB: Ks/Vs 9K + QPs 18K (Q stage -> per-wave P region).
// =====================================================================
__global__ __launch_bounds__(256)
void attn_mfma(const __bf16* __restrict__ Qg, const __bf16* __restrict__ Kg,
               const __bf16* __restrict__ Vtg, __bf16* __restrict__ Zm)
{
    const int bh = blockIdx.y;
    const int q0 = blockIdx.x * 128;
    const size_t base = (size_t)bh * TTOK * 64;

    __shared__ __attribute__((aligned(16))) __bf16 Ks[64 * 72];
    __shared__ __attribute__((aligned(16))) __bf16 Vs[64 * 72];
    __shared__ __attribute__((aligned(16))) __bf16 QPs[128 * 72];

    const int tid  = threadIdx.x;
    const int lane = tid & 63, wave = tid >> 6;   // wave 0..3
    const int c32  = lane & 31, h32 = lane >> 5;

    // ---- stage Q (pre-scaled by QSCALE in GEMM): 128 rows x 64 ----
#pragma unroll
    for (int it = 0; it < 2; ++it) {
        int idx = tid + 256 * it;              // 0..511
        int r = idx >> 2, off = (idx & 3) * 16;
        const __bf16* src = Qg + base + (size_t)(q0 + r) * 64 + off;
        *(bf16x8*)&QPs[r * 72 + off]     = *(const bf16x8*)(src);
        *(bf16x8*)&QPs[r * 72 + off + 8] = *(const bf16x8*)(src + 8);
    }
    __syncthreads();
    bf16x8 qf[4];
#pragma unroll
    for (int st = 0; st < 4; ++st)
        qf[st] = *(const bf16x8*)&QPs[(wave * 32 + c32) * 72 + h32 * 8 + st * 16];
    // wave w reuses rows [32w,32w+32) as its P region (only rows it read)

    bf16x8 ones;
#pragma unroll
    for (int i = 0; i < 8; ++i) ones[i] = (__bf16)1.0f;

    f32x16 O[2], lacc;
#pragma unroll
    for (int r = 0; r < 16; ++r) { O[0][r] = 0.0f; O[1][r] = 0.0f; lacc[r] = 0.0f; }

    const int rs = tid >> 2, soff = (tid & 3) * 16;   // 64 rows x 64, 2 b128/thread

    // prefetch tile 0
    bf16x8 kr0 = *(const bf16x8*)(Kg  + base + (size_t)rs * 64 + soff);
    bf16x8 kr1 = *(const bf16x8*)(Kg  + base + (size_t)rs * 64 + soff + 8);
    bf16x8 vr0 = *(const bf16x8*)(Vtg + base + (size_t)rs * TTOK + soff);
    bf16x8 vr1 = *(const bf16x8*)(Vtg + base + (size_t)rs * TTOK + soff + 8);

    // epilogue V snapshot coords: wave's q-rows live in key-tile kb_tgt
    const int kb_tgt = (q0 >> 6) + (wave >> 1);
    const int qo     = (wave & 1) * 32 + c32;
    float vq[2][16];

    for (int kb = 0; kb < TTOK / 64; ++kb) {
        __syncthreads();   // prior tile's Ks/Vs frag reads complete
        *(bf16x8*)&Ks[rs * 72 + soff]     = kr0;
        *(bf16x8*)&Ks[rs * 72 + soff + 8] = kr1;
        *(bf16x8*)&Vs[rs * 72 + soff]     = vr0;
        *(bf16x8*)&Vs[rs * 72 + soff + 8] = vr1;
        __syncthreads();

        // prefetch next tile — latency spans the compute below
        {
            int kbn = (kb + 1) & (TTOK / 64 - 1);
            const __bf16* kp = Kg  + base + (size_t)(kbn * 64 + rs) * 64 + soff;
            const __bf16* vp = Vtg + base + (size_t)rs * TTOK + kbn * 64 + soff;
            kr0 = *(const bf16x8*)(kp); kr1 = *(const bf16x8*)(kp + 8);
            vr0 = *(const bf16x8*)(vp); vr1 = *(const bf16x8*)(vp + 8);
        }

        // ---- S^T = K·Q^T ----
        f32x16 s0, s1;
#pragma unroll
        for (int r = 0; r < 16; ++r) { s0[r] = 0.0f; s1[r] = 0.0f; }
#pragma unroll
        for (int st = 0; st < 4; ++st) {
            bf16x8 a0 = *(const bf16x8*)&Ks[(c32)      * 72 + h32 * 8 + st * 16];
            bf16x8 a1 = *(const bf16x8*)&Ks[(32 + c32) * 72 + h32 * 8 + st * 16];
            s0 = __builtin_amdgcn_mfma_f32_32x32x16_bf16(a0, qf[st], s0, 0, 0, 0);
            s1 = __builtin_amdgcn_mfma_f32_32x32x16_bf16(a1, qf[st], s1, 0, 0, 0);
        }

        // ---- p = exp2(s); write P[q][key] (b64) ----
#pragma unroll
        for (int kb2 = 0; kb2 < 2; ++kb2) {
#pragma unroll
            for (int g = 0; g < 4; ++g) {
                float p0 = EXP2F(kb2 ? s1[4 * g + 0] : s0[4 * g + 0]);
                float p1 = EXP2F(kb2 ? s1[4 * g + 1] : s0[4 * g + 1]);
                float p2 = EXP2F(kb2 ? s1[4 * g + 2] : s0[4 * g + 2]);
                float p3 = EXP2F(kb2 ? s1[4 * g + 3] : s0[4 * g + 3]);
                bf16x4 pk;
                pk[0] = (__bf16)p0; pk[1] = (__bf16)p1;
                pk[2] = (__bf16)p2; pk[3] = (__bf16)p3;
                *(bf16x4*)&QPs[(wave * 32 + c32) * 72 + kb2 * 32 + g * 8 + h32 * 4] = pk;
            }
        }

        // ---- O^T += V^T·P ; l += 1·P ----
#pragma unroll
        for (int ks = 0; ks < 4; ++ks) {
            bf16x8 pf = *(const bf16x8*)&QPs[(wave * 32 + c32) * 72 + h32 * 8 + ks * 16];
            lacc = __builtin_amdgcn_mfma_f32_32x32x16_bf16(ones, pf, lacc, 0, 0, 0);
            bf16x8 v0 = *(const bf16x8*)&Vs[(c32)      * 72 + h32 * 8 + ks * 16];
            bf16x8 v1 = *(const bf16x8*)&Vs[(32 + c32) * 72 + h32 * 8 + ks * 16];
            O[0] = __builtin_amdgcn_mfma_f32_32x32x16_bf16(v0, pf, O[0], 0, 0, 0);
            O[1] = __builtin_amdgcn_mfma_f32_32x32x16_bf16(v1, pf, O[1], 0, 0, 0);
        }

        // ---- snapshot own-q V column from LDS (wave-uniform branch) ----
        if (kb == kb_tgt) {
#pragma unroll
            for (int db = 0; db < 2; ++db)
#pragma unroll
                for (int rg = 0; rg < 16; ++rg) {
                    int d = db * 32 + (rg & 3) + 8 * (rg >> 2) + 4 * h32;
                    vq[db][rg] = (float)Vs[d * 72 + qo];
                }
        }
    }

    const float inv = 1.0f / lacc[0];

    // ---- epilogue: Y = O/l ; exclusive output mod ; packed bf16 store ----
    const int b = bh >> 4, h = bh & 15;
    const int q = q0 + wave * 32 + c32;
    float y[2][16];
    float yv = 0.f, v2 = 0.f, yy = 0.f;
#pragma unroll
    for (int db = 0; db < 2; ++db)
#pragma unroll
        for (int rg = 0; rg < 16; ++rg) {
            float yval = O[db][rg] * inv;
            float vval = vq[db][rg];
            y[db][rg] = yval;
            yv += yval * vval; v2 += vval * vval; yy += yval * yval;
        }
    yv += __shfl_xor(yv, 32, 64);
    v2 += __shfl_xor(v2, 32, 64);
    yy += __shfl_xor(yy, 32, 64);
    float scl = (v2 > 0.0f) ? yv / fmaxf(v2, 1.1754943508222875e-38f) : 0.0f;
    float zz = 0.f;
    float zvv[2][16];
#pragma unroll
    for (int db = 0; db < 2; ++db)
#pragma unroll
        for (int rg = 0; rg < 16; ++rg) {
            zvv[db][rg] = y[db][rg] - scl * vq[db][rg];
            zz += zvv[db][rg] * zvv[db][rg];
        }
    zz += __shfl_xor(zz, 32, 64);
    float znorm = sqrtf(zz);
    float refn  = fmaxf(sqrtf(yy), sqrtf(v2));
    bool  wipe  = (v2 > 0.0f) && (znorm <= 1.1920928955078125e-07f * 64.0f * refn);
#pragma unroll
    for (int db = 0; db < 2; ++db)
#pragma unroll
        for (int g = 0; g < 4; ++g) {
            bf16x4 pk;
#pragma unroll
            for (int r = 0; r < 4; ++r)
                pk[r] = (__bf16)(wipe ? 0.0f : zvv[db][4 * g + r]);
            int d = db * 32 + 8 * g + 4 * h32;
            *(bf16x4*)&Zm[((size_t)(b * TTOK + q)) * DM + h * 64 + d] = pk;
        }
}

// =====================================================================
extern "C" void kernel_launch(void* const* d_in, const int* in_sizes, int n_in,
                              void* d_out, int out_size, void* d_ws, size_t ws_size,
                              hipStream_t stream) {
    const float* x  = (const float*)d_in[0];
    const float* Wq = (const float*)d_in[1];
    const float* Wk = (const float*)d_in[2];
    const float* Wv = (const float*)d_in[3];
    const float* Wo = (const float*)d_in[4];

    const size_t NX = (size_t)NTOK * DM;   // 4M
    const size_t NW = (size_t)DM * DM;     // 1M
    __bf16* xb  = (__bf16*)d_ws;
    __bf16* wqb = xb  + NX;
    __bf16* wkb = wqb + NW;
    __bf16* wvb = wkb + NW;
    __bf16* wob = wvb + NW;
    __bf16* Qb  = wob + NW;
    __bf16* Kb  = Qb  + NX;
    __bf16* Vtb = Kb  + NX;
    __bf16* Zmb = Vtb + NX;   // total 24M bf16 = 48 MB

    cvt_all<<<(NX + 4 * NW) / 2048, 256, 0, stream>>>(x, Wq, Wk, Wv, Wo, xb);

    // QKV: z0/z1 = Wq,Wk · x^T ; z2 = x · Wv^T  (LDS-transpose epilogues)
    gemm_bf16<0><<<dim3(32, 8, 3), 256, 0, stream>>>(
        xb, wqb, wkb, wvb, Qb, Kb, Vtb, nullptr);

    attn_mfma<<<dim3(TTOK / 128, 32), 256, 0, stream>>>(Qb, Kb, Vtb, Zmb);

    // out = Zm · Wo^T (m=token, n=Dout; scalar n-fastest stores)
    gemm_bf16<1><<<dim3(8, 32), 256, 0, stream>>>(
        Zmb, wob, nullptr, nullptr, nullptr, nullptr, nullptr, (float*)d_out);
}